// Round 2
// baseline (406.403 us; speedup 1.0000x reference)
//
#include <hip/hip_runtime.h>

#define NQ 5
#define NL 6
#define NG 4
#define DIM 32          // 2^NQ
#define PATCH 16        // rows with q0=0
#define MSZ (NG*PATCH*DIM)   // 2048 floats = 8 KB

// CZ-chain sign: flip amplitude i iff # adjacent set-bit pairs is odd.
__device__ __forceinline__ int flip_par(int i) {
    int p = i & (i >> 1) & 0xF;
    p ^= p >> 2; p ^= p >> 1;
    return p & 1;
}

// Stage 1: build M_g[r,i] = (R_L S R_{L-1} S ... S R_1)[r,i], rows 0..15 only.
// 128 threads: thread = (g<<5)|col simulates the circuit on basis vector e_col.
__global__ void build_M(const float* __restrict__ qp, float* __restrict__ M) {
    const float RV = 0.07957747154594767f; // 0.5/(2*pi): v_sin/v_cos take revolutions
    const int tid = threadIdx.x;
    if (tid >= NG * DIM) return;
    const int g = tid >> 5, col = tid & 31;
    float st[DIM];
    #pragma unroll
    for (int i = 0; i < DIM; ++i) st[i] = (i == col) ? 1.0f : 0.0f;
    #pragma unroll 1
    for (int l = 0; l < NL; ++l) {
        #pragma unroll            // w MUST be unrolled: st[] indices stay compile-time
        for (int w = 0; w < NQ; ++w) {
            float h = qp[g*(NL*NQ) + l*NQ + w] * RV;
            float c = __builtin_amdgcn_cosf(h);
            float s = __builtin_amdgcn_sinf(h);
            const int bit = 4 - w, str = 1 << bit;
            #pragma unroll
            for (int p = 0; p < 16; ++p) {
                int lo = ((p >> bit) << (bit + 1)) | (p & (str - 1));
                int hi = lo + str;
                float a0 = st[lo], a1 = st[hi];
                st[lo] = c*a0 - s*a1;
                st[hi] = s*a0 + c*a1;
            }
        }
        if (l != NL - 1) {        // outermost sign layer dies in |.|^2
            #pragma unroll
            for (int i = 0; i < DIM; ++i)
                if (flip_par(i)) st[i] = -st[i];
        }
    }
    #pragma unroll
    for (int r = 0; r < PATCH; ++r)
        M[(g*PATCH + r)*DIM + col] = st[r];
}

// Stage 2: amp[b,g,r] = sum_i M_g[r,i] * prod_w (bit_w(i) ? sin(x_w/2) : cos(x_w/2))
// contracted qubit-by-qubit (never materializes the product state).
__global__ __launch_bounds__(256) void qgen2(
        const float* __restrict__ x, const float* __restrict__ M,
        float* __restrict__ out, int B) {
    __shared__ float lm[MSZ];
    {   // 2048 floats / 256 threads = 2 float4 each
        const float4* src = (const float4*)M;
        float4* dst = (float4*)lm;
        dst[threadIdx.x]       = src[threadIdx.x];
        dst[threadIdx.x + 256] = src[threadIdx.x + 256];
    }
    __syncthreads();

    const int b = blockIdx.x * blockDim.x + threadIdx.x;
    if (b >= B) return;

    const float RV = 0.07957747154594767f;
    float cn[NQ], sn[NQ];
    #pragma unroll
    for (int w = 0; w < NQ; ++w) {
        float h = x[(size_t)b * NQ + w] * RV;
        cn[w] = __builtin_amdgcn_cosf(h);
        sn[w] = __builtin_amdgcn_sinf(h);
    }

    float* og = out + (size_t)b * (NG * PATCH);

    #pragma unroll 1
    for (int g = 0; g < NG; ++g) {
        float amp[PATCH];
        #pragma unroll
        for (int r = 0; r < PATCH; ++r) {
            const float* mr = &lm[(g*PATCH + r) * DIM];
            float T[16];
            // contract q4 (bit 0): 32 -> 16, reading M row as 8x float4 (broadcast)
            #pragma unroll
            for (int k = 0; k < 8; ++k) {
                float4 m4 = *(const float4*)&mr[4*k];
                T[2*k]   = m4.x*cn[4] + m4.y*sn[4];
                T[2*k+1] = m4.z*cn[4] + m4.w*sn[4];
            }
            #pragma unroll
            for (int j = 0; j < 8; ++j) T[j] = T[2*j]*cn[3] + T[2*j+1]*sn[3];
            #pragma unroll
            for (int j = 0; j < 4; ++j) T[j] = T[2*j]*cn[2] + T[2*j+1]*sn[2];
            #pragma unroll
            for (int j = 0; j < 2; ++j) T[j] = T[2*j]*cn[1] + T[2*j+1]*sn[1];
            amp[r] = T[0]*cn[0] + T[1]*sn[0];
        }
        // out = p[:16] / max(p[:16])  (sum normalization cancels)
        float p0[PATCH];
        #pragma unroll
        for (int i = 0; i < PATCH; ++i) p0[i] = amp[i] * amp[i];
        float mx = p0[0];
        #pragma unroll
        for (int i = 1; i < PATCH; ++i) mx = fmaxf(mx, p0[i]);
        float inv = __builtin_amdgcn_rcpf(mx);
        float4* o4 = (float4*)(og + g * PATCH);
        #pragma unroll
        for (int k = 0; k < 4; ++k)
            o4[k] = make_float4(p0[4*k]*inv, p0[4*k+1]*inv, p0[4*k+2]*inv, p0[4*k+3]*inv);
    }
}

extern "C" void kernel_launch(void* const* d_in, const int* in_sizes, int n_in,
                              void* d_out, int out_size, void* d_ws, size_t ws_size,
                              hipStream_t stream) {
    const float* x  = (const float*)d_in[0];
    const float* qp = (const float*)d_in[1];
    float* out = (float*)d_out;
    float* M = (float*)d_ws;            // 8 KB of scratch
    const int B = in_sizes[0] / NQ;
    build_M<<<1, 128, 0, stream>>>(qp, M);
    qgen2<<<(B + 255) / 256, 256, 0, stream>>>(x, M, out, B);
}

// Round 3
// 42.535 us; speedup vs baseline: 9.5546x; 9.5546x over previous
//
#include <hip/hip_runtime.h>

#define NQ 5
#define NL 6
#define NG 4
#define DIM 32            // 2^NQ
#define PATCH 16          // rows with q0=0
#define MSZ (NG*PATCH*DIM) // 2048 floats = 8 KB

// CZ-chain sign: flip amplitude i iff # adjacent set-bit pairs is odd.
__device__ __forceinline__ int flip_par(int i) {
    int p = i & (i >> 1) & 0xF;
    p ^= p >> 2; p ^= p >> 1;
    return p & 1;
}

// Stage 1: M_g[r,i] = weight-circuit operator, rows 0..15 (q0=0 slice).
// 128 threads: thread = (g<<5)|col simulates basis vector e_col. Proven in R1/R2.
__global__ void build_M(const float* __restrict__ qp, float* __restrict__ M) {
    const float RV = 0.07957747154594767f; // 0.5/(2*pi): v_sin/v_cos take revolutions
    const int tid = threadIdx.x;
    if (tid >= NG * DIM) return;
    const int g = tid >> 5, col = tid & 31;
    float st[DIM];
    #pragma unroll
    for (int i = 0; i < DIM; ++i) st[i] = (i == col) ? 1.0f : 0.0f;
    #pragma unroll 1
    for (int l = 0; l < NL; ++l) {
        #pragma unroll          // w unrolled: st[] indices stay compile-time
        for (int w = 0; w < NQ; ++w) {
            float h = qp[g*(NL*NQ) + l*NQ + w] * RV;
            float c = __builtin_amdgcn_cosf(h);
            float s = __builtin_amdgcn_sinf(h);
            const int bit = 4 - w, str = 1 << bit;
            #pragma unroll
            for (int p = 0; p < 16; ++p) {
                int lo = ((p >> bit) << (bit + 1)) | (p & (str - 1));
                int hi = lo + str;
                float a0 = st[lo], a1 = st[hi];
                st[lo] = c*a0 - s*a1;
                st[hi] = s*a0 + c*a1;
            }
        }
        if (l != NL - 1) {      // outermost sign layer dies in |.|^2
            #pragma unroll
            for (int i = 0; i < DIM; ++i)
                if (flip_par(i)) st[i] = -st[i];
        }
    }
    #pragma unroll
    for (int r = 0; r < PATCH; ++r)
        M[(g*PATCH + r)*DIM + col] = st[r];
}

// Stage 2: amp[b,g,r] = dot(M_g[r,:], base[b,:]) where base is the rank-1
// product state of the noise RYs. p = amp^2; out = p / max_r p (sum cancels).
__global__ __launch_bounds__(256, 3) void qgen2(
        const float* __restrict__ x, const float* __restrict__ M,
        float* __restrict__ out, int B) {
    __shared__ float  lm[MSZ];          // 8 KB: M, broadcast-read
    __shared__ float4 stg[256 * 16];    // 64 KB: staged p, XOR-swizzled f4 slots
    __shared__ float  linv[256 * 4];    // 4 KB: per (thread, g) 1/max

    const int t = threadIdx.x;
    {   // load M: 2048 floats = 2 float4 per thread
        const float4* src = (const float4*)M;
        float4* dst = (float4*)lm;
        dst[t]       = src[t];
        dst[t + 256] = src[t + 256];
    }
    __syncthreads();

    const int b = blockIdx.x * 256 + t;   // B == 262144 == 1024*256, no tail

    const float RV = 0.07957747154594767f;
    float cn[NQ], sn[NQ];
    #pragma unroll
    for (int w = 0; w < NQ; ++w) {
        float h = x[(size_t)b * NQ + w] * RV;
        cn[w] = __builtin_amdgcn_cosf(h);
        sn[w] = __builtin_amdgcn_sinf(h);
    }

    // product state (62 mults), shared by all 4 generators
    float base[DIM];
    base[0] = cn[0]; base[1] = sn[0];
    #pragma unroll
    for (int w = 1; w < NQ; ++w) {
        #pragma unroll
        for (int j = (1 << w) - 1; j >= 0; --j) {
            float v = base[j];
            base[2*j + 1] = v * sn[w];
            base[2*j]     = v * cn[w];
        }
    }

    #pragma unroll 1
    for (int g = 0; g < NG; ++g) {
        float mx = 0.0f;                  // p >= 0, so 0 is a safe identity
        #pragma unroll 1
        for (int r4 = 0; r4 < 4; ++r4) {
            float pj[4];                  // static-indexed only (j unrolled)
            #pragma unroll
            for (int j = 0; j < 4; ++j) {
                const float* mr = &lm[(g*PATCH + r4*4 + j) * DIM];
                float a0 = 0.f, a1 = 0.f, a2 = 0.f, a3 = 0.f;
                #pragma unroll
                for (int q = 0; q < 8; ++q) {   // broadcast LDS float4 reads
                    float4 m4 = *(const float4*)&mr[4*q];
                    a0 = fmaf(m4.x, base[4*q],     a0);
                    a1 = fmaf(m4.y, base[4*q + 1], a1);
                    a2 = fmaf(m4.z, base[4*q + 2], a2);
                    a3 = fmaf(m4.w, base[4*q + 3], a3);
                }
                float amp = (a0 + a1) + (a2 + a3);
                float p = amp * amp;
                mx = fmaxf(mx, p);
                pj[j] = p;
            }
            int s = g*4 + r4;             // logical f4 slot 0..15
            stg[t*16 + (s ^ (t & 15))] = make_float4(pj[0], pj[1], pj[2], pj[3]);
        }
        linv[t*4 + g] = __builtin_amdgcn_rcpf(mx);
    }
    __syncthreads();

    // cooperative coalesced write: block's 64 KB region, 1 KB per wave-instr
    float4* og = (float4*)(out + (size_t)blockIdx.x * (256 * 64));
    #pragma unroll
    for (int k = 0; k < 16; ++k) {
        int f  = t + 256 * k;             // f4 index in block region
        int bl = f >> 4;                  // local batch 0..255
        int s  = f & 15;                  // logical slot
        float4 v  = stg[bl*16 + (s ^ (bl & 15))];
        float inv = linv[bl*4 + (s >> 2)];
        og[f] = make_float4(v.x*inv, v.y*inv, v.z*inv, v.w*inv);
    }
}

extern "C" void kernel_launch(void* const* d_in, const int* in_sizes, int n_in,
                              void* d_out, int out_size, void* d_ws, size_t ws_size,
                              hipStream_t stream) {
    const float* x  = (const float*)d_in[0];
    const float* qp = (const float*)d_in[1];
    float* out = (float*)d_out;
    float* M = (float*)d_ws;              // 8 KB scratch
    const int B = in_sizes[0] / NQ;
    build_M<<<1, 128, 0, stream>>>(qp, M);
    qgen2<<<(B + 255) / 256, 256, 0, stream>>>(x, M, out, B);
}

// Round 4
// 38.884 us; speedup vs baseline: 10.4516x; 1.0939x over previous
//
#include <hip/hip_runtime.h>

#define NQ 5
#define NL 6
#define NG 4
#define DIM 32
#define PATCH 16
#define STG_PITCH 20   // floats per batch in LDS staging (16 + pad; 80 B, 16B-aligned)

// CZ-chain sign: flip amplitude i iff # adjacent set-bit pairs is odd.
__device__ __forceinline__ int flip_par(int i) {
    int p = i & (i >> 1) & 0xF;
    p ^= p >> 2; p ^= p >> 1;
    return p & 1;
}

// Stage 1: M_g[r,i] = weight-circuit operator, rows 0..15 (q0=0 slice).
// 128 threads: thread = (g<<5)|col simulates basis vector e_col. Verified R1-R3.
__global__ void build_M(const float* __restrict__ qp, float* __restrict__ M) {
    const float RV = 0.07957747154594767f; // 0.5/(2*pi): v_sin/v_cos take revolutions
    const int tid = threadIdx.x;
    if (tid >= NG * DIM) return;
    const int g = tid >> 5, col = tid & 31;
    float st[DIM];
    #pragma unroll
    for (int i = 0; i < DIM; ++i) st[i] = (i == col) ? 1.0f : 0.0f;
    #pragma unroll 1
    for (int l = 0; l < NL; ++l) {
        #pragma unroll          // w unrolled: st[] indices stay compile-time
        for (int w = 0; w < NQ; ++w) {
            float h = qp[g*(NL*NQ) + l*NQ + w] * RV;
            float c = __builtin_amdgcn_cosf(h);
            float s = __builtin_amdgcn_sinf(h);
            const int bit = 4 - w, str = 1 << bit;
            #pragma unroll
            for (int p = 0; p < 16; ++p) {
                int lo = ((p >> bit) << (bit + 1)) | (p & (str - 1));
                int hi = lo + str;
                float a0 = st[lo], a1 = st[hi];
                st[lo] = c*a0 - s*a1;
                st[hi] = s*a0 + c*a1;
            }
        }
        if (l != NL - 1) {      // outermost sign layer dies in |.|^2
            #pragma unroll
            for (int i = 0; i < DIM; ++i)
                if (flip_par(i)) st[i] = -st[i];
        }
    }
    #pragma unroll
    for (int r = 0; r < PATCH; ++r)
        M[(g*PATCH + r)*DIM + col] = st[r];
}

// Stage 2: lane = batch. base[32] private in VGPRs; M rows stream through
// SGPRs (s_load, sL1-cached, shared CU-wide); dot = v_fmac(v,s,v).
// Max over a generator's 16 rows is a within-lane fmax chain. LDS only for a
// per-wave 4.6 KB transpose so global stores are full-line coalesced.
__global__ __launch_bounds__(256, 6) void qgen3(
        const float* __restrict__ x, const float* __restrict__ M,
        float* __restrict__ out) {
    __shared__ __align__(16) float stg[4][64 * STG_PITCH + 64];  // 21.5 KB

    const int t = threadIdx.x;
    const int wid = t >> 6, lane = t & 63;
    const int b0 = (blockIdx.x * 4 + wid) * 64;

    const float RV = 0.07957747154594767f;
    float cn[NQ], sn[NQ];
    const float* xp = x + (size_t)(b0 + lane) * NQ;
    #pragma unroll
    for (int w = 0; w < NQ; ++w) {
        float h = xp[w] * RV;
        cn[w] = __builtin_amdgcn_cosf(h);
        sn[w] = __builtin_amdgcn_sinf(h);
    }
    // product state of the noise RYs (62 mults), private per lane
    float base[DIM];
    base[0] = cn[0]; base[1] = sn[0];
    #pragma unroll
    for (int w = 1; w < NQ; ++w) {
        #pragma unroll
        for (int j = (1 << w) - 1; j >= 0; --j) {
            float v = base[j];
            base[2*j + 1] = v * sn[w];
            base[2*j]     = v * cn[w];
        }
    }

    float* sw  = stg[wid];
    float* inw = sw + 64 * STG_PITCH;
    float* ow  = out + (size_t)b0 * 64;

    #pragma unroll 1
    for (int g = 0; g < NG; ++g) {
        float mx = 0.0f;                       // p >= 0: safe identity
        #pragma unroll 1
        for (int r4 = 0; r4 < 4; ++r4) {       // 4 rows per chunk -> one b128 write
            float pv[4];
            #pragma unroll
            for (int j = 0; j < 4; ++j) {
                int row = __builtin_amdgcn_readfirstlane(g*PATCH + r4*4 + j);
                const float* mp = M + (row << 5);   // wave-uniform -> s_load
                float ms[DIM];
                #pragma unroll
                for (int i = 0; i < DIM; ++i) ms[i] = mp[i];
                float a0=0.f, a1=0.f, a2=0.f, a3=0.f;
                #pragma unroll
                for (int q = 0; q < 8; ++q) {
                    a0 = fmaf(ms[4*q+0], base[4*q+0], a0);
                    a1 = fmaf(ms[4*q+1], base[4*q+1], a1);
                    a2 = fmaf(ms[4*q+2], base[4*q+2], a2);
                    a3 = fmaf(ms[4*q+3], base[4*q+3], a3);
                }
                float amp = (a0 + a1) + (a2 + a3);
                pv[j] = amp * amp;
                mx = fmaxf(mx, pv[j]);
            }
            *(float4*)&sw[lane * STG_PITCH + r4 * 4] =
                make_float4(pv[0], pv[1], pv[2], pv[3]);
        }
        inw[lane] = __builtin_amdgcn_rcpf(mx);
        // Same-wave LDS RAW: in-order DS per wave; compiler inserts lgkmcnt.
        // No barrier: each wave touches only its own stg slice.
        #pragma unroll
        for (int j = 0; j < 4; ++j) {
            int bl = (lane >> 2) + 16 * j;     // local batch
            int f  = lane & 3;                 // float4 slot
            float4 v = *(const float4*)&sw[bl * STG_PITCH + f * 4];
            float iv = inw[bl];
            *(float4*)&ow[bl*64 + g*16 + f*4] =
                make_float4(v.x*iv, v.y*iv, v.z*iv, v.w*iv);
        }
    }
}

extern "C" void kernel_launch(void* const* d_in, const int* in_sizes, int n_in,
                              void* d_out, int out_size, void* d_ws, size_t ws_size,
                              hipStream_t stream) {
    const float* x  = (const float*)d_in[0];
    const float* qp = (const float*)d_in[1];
    float* out = (float*)d_out;
    float* M = (float*)d_ws;                   // 8 KB scratch
    const int B = in_sizes[0] / NQ;
    build_M<<<1, 128, 0, stream>>>(qp, M);
    qgen3<<<B / 256, 256, 0, stream>>>(x, M, out);
}